// Round 1
// 311.529 us; speedup vs baseline: 1.0192x; 1.0192x over previous
//
#include <hip/hip_runtime.h>
#include <cstdint>
#include <cstddef>

#define B_  4
#define S_  2048
#define D_  1024
#define H_  16
#define HD_ 64
#define M_  (B_ * S_)   // 8192 rows

#define CHUNKS_ 64      // parallel chunks per (b,h) sequence
#define CL_     32      // chunk length; CHUNKS_*CL_ == S_

typedef __bf16 bf16_t;
typedef bf16_t bf16x8 __attribute__((ext_vector_type(8)));
typedef float  floatx4 __attribute__((ext_vector_type(4)));

// ---------------------------------------------------------------------------
// async 16B global -> LDS copy (gfx950). LDS dest is wave-uniform base +
// lane*16 (m104/m108); all uses below pass lds = base + lane*16 exactly.
// ---------------------------------------------------------------------------
__device__ __forceinline__ void async_copy16(const void* gmem, void* lds) {
  __builtin_amdgcn_global_load_lds(
      (__attribute__((address_space(1))) void*)const_cast<void*>(gmem),
      (__attribute__((address_space(3))) void*)lds,
      16, 0, 0);
}

// ---------------------------------------------------------------------------
// Fused prologue: weight fp32->bf16 cast (4M elems) + token-shift mix (8M).
// ---------------------------------------------------------------------------
__global__ void pre_kernel(const float* __restrict__ w0, const float* __restrict__ w1,
                           const float* __restrict__ w2, const float* __restrict__ w3,
                           bf16_t* __restrict__ wout,
                           const float* __restrict__ x,
                           const float* __restrict__ tmr, const float* __restrict__ tmk,
                           const float* __restrict__ tmv,
                           bf16_t* __restrict__ xr, bf16_t* __restrict__ xk,
                           bf16_t* __restrict__ xv) {
  const int ONE_M = 1 << 20;
  int gid = blockIdx.x * blockDim.x + threadIdx.x;
  if (gid < 4 * ONE_M) {
    const float* src = (gid < ONE_M) ? w0 : (gid < 2 * ONE_M) ? w1 : (gid < 3 * ONE_M) ? w2 : w3;
    wout[gid] = (bf16_t)src[gid & (ONE_M - 1)];
  } else {
    int idx = gid - 4 * ONE_M;                 // 0 .. 8M-1
    int d = idx & (D_ - 1);
    int t = (idx / D_) & (S_ - 1);
    float xc = x[idx];
    float xp = (t == 0) ? 0.0f : x[idx - D_];
    float mr = tmr[d], mk = tmk[d], mv = tmv[d];
    xr[idx] = (bf16_t)(xc * mr + xp * (1.0f - mr));
    xk[idx] = (bf16_t)(xc * mk + xp * (1.0f - mk));
    xv[idx] = (bf16_t)(xc * mv + xp * (1.0f - mv));
  }
}

// ---------------------------------------------------------------------------
// r9: counted-vmcnt deep-pipelined GEMM core (T3+T4), 3-slot LDS rotation.
//   BM=256 BN=128 BK=64, 512 thr / 8 waves (4M x 2N), per-wave 64x64.
//   LDS 144 KiB (3 x (32K A + 16K B)) -> 1 block/CU.
//   T2 swizzle: LDS col byte ^= (row&7)<<4, applied on BOTH sides
//   (pre-swizzled global source for linear global_load_lds dest + swizzled
//   ds_read address, rule #21) -> uniform 8 lanes / 16B slot, min-cycle b128.
//   Main loop: stage tile t+2, read tile t, 32 MFMA, s_waitcnt vmcnt(6)
//   (= 6 loads/tile * 1 older tile in flight stays outstanding), raw
//   s_barrier. vmcnt drains to 0 only once, at the last prefetched tile.
// ---------------------------------------------------------------------------
#define G3_STAGE(kt, la, lb) do {                                          \
    const char* _ga = Abase + (size_t)(kt) * 128;                          \
    const char* _gb = Bbase + (size_t)(kt) * 128;                          \
    _Pragma("unroll")                                                      \
    for (int _i = 0; _i < 4; ++_i)                                         \
      async_copy16(_ga + (size_t)(_i * 64 + r8) * 2048 + cbs,              \
                   (la) + _i * 8192 + tid * 16);                           \
    _Pragma("unroll")                                                      \
    for (int _i = 0; _i < 2; ++_i)                                         \
      async_copy16(_gb + (size_t)(_i * 64 + r8) * 2048 + cbs,              \
                   (lb) + _i * 8192 + tid * 16);                           \
  } while (0)

#define G3_COMPUTE(la, lb) do {                                            \
    bf16x8 _af[4][2], _bfr[4][2];                                          \
    _Pragma("unroll")                                                      \
    for (int _i = 0; _i < 4; ++_i) {                                       \
      const char* _ra = (la) + (wm * 64 + _i * 16 + l15) * 128;            \
      const char* _rb = (lb) + (wn * 64 + _i * 16 + l15) * 128;            \
      _Pragma("unroll")                                                    \
      for (int _k = 0; _k < 2; ++_k) {                                     \
        const int _c = (_k * 64 + quad * 16) ^ swz;                        \
        _af[_i][_k]  = *(const bf16x8*)(_ra + _c);                         \
        _bfr[_i][_k] = *(const bf16x8*)(_rb + _c);                         \
      }                                                                    \
    }                                                                      \
    _Pragma("unroll")                                                      \
    for (int _k = 0; _k < 2; ++_k)                                         \
      _Pragma("unroll")                                                    \
      for (int _i = 0; _i < 4; ++_i)                                       \
        _Pragma("unroll")                                                  \
        for (int _j = 0; _j < 4; ++_j)                                     \
          acc[_i][_j] = __builtin_amdgcn_mfma_f32_16x16x32_bf16(           \
              _af[_i][_k], _bfr[_j][_k], acc[_i][_j], 0, 0, 0);            \
  } while (0)

// counted vmcnt + raw barrier; asm memory clobbers fence compiler reordering
// of LDS reads / stage issues across the barrier (rule #18/#21 discipline).
#define FENCE_BAR(N) do {                                                  \
    asm volatile("s_waitcnt vmcnt(" #N ")" ::: "memory");                  \
    __builtin_amdgcn_s_barrier();                                          \
    asm volatile("" ::: "memory");                                         \
  } while (0)

template <typename CT>
__device__ __forceinline__ void gemm_core(const bf16_t* __restrict__ A,
                                          const bf16_t* __restrict__ Bw,
                                          CT* __restrict__ C, int m0, int n0) {
  __shared__ __align__(16) bf16_t As[3][256][64];   // 96 KiB
  __shared__ __align__(16) bf16_t Bs[3][128][64];   // 48 KiB

  const int tid  = threadIdx.x;
  const int lane = tid & 63;
  const int wave = tid >> 6;       // 0..7
  const int wm   = wave >> 1;      // 0..3  (M)
  const int wn   = wave & 1;       // 0..1  (N)
  const int l15  = lane & 15;
  const int quad = lane >> 4;
  const int r8   = tid >> 3;                       // staging row-within-64
  const int cbs  = (((tid & 7) ^ (r8 & 7)) << 4);  // pre-swizzled src col
  const int swz  = (l15 & 7) << 4;                 // read-side XOR

  const char* Abase = (const char*)(A + (size_t)m0 * D_);
  const char* Bbase = (const char*)(Bw + (size_t)n0 * D_);

  char* const a0 = (char*)&As[0][0][0];
  char* const a1 = a0 + 32768;
  char* const a2 = a1 + 32768;
  char* const b0 = (char*)&Bs[0][0][0];
  char* const b1 = b0 + 16384;
  char* const b2 = b1 + 16384;

  floatx4 acc[4][4] = {};

  // prologue: tiles 0,1 in flight; wait tile0 (own 6 of 12) then barrier
  G3_STAGE(0, a0, b0);
  G3_STAGE(1, a1, b1);
  FENCE_BAR(6);

  char *aC = a0, *aN = a1, *aF = a2;
  char *bC = b0, *bN = b1, *bF = b2;

  // K = 1024 -> 16 tiles of BK=64. Main loop covers t=0..13 (t+2 <= 15).
#pragma unroll 1
  for (int t = 0; t < 14; ++t) {
    G3_STAGE(t + 2, aF, bF);     // slot (t+2)%3: last read at iter t-1
    G3_COMPUTE(aC, bC);
    FENCE_BAR(6);                // tile t+1's 6 loads landed; t+2's in flight
    char* x;
    x = aC; aC = aN; aN = aF; aF = x;
    x = bC; bC = bN; bN = bF; bF = x;
  }
  // t = 14: nothing left to stage; must drain tile15's loads
  G3_COMPUTE(aC, bC);
  FENCE_BAR(0);
  // t = 15
  G3_COMPUTE(aN, bN);

#pragma unroll
  for (int i = 0; i < 4; ++i) {
#pragma unroll
    for (int j = 0; j < 4; ++j) {
      int row = m0 + wm * 64 + i * 16 + quad * 4;
      int col = n0 + wn * 64 + j * 16 + l15;
      CT* Cp = C + (size_t)row * D_ + col;
#pragma unroll
      for (int r = 0; r < 4; ++r)
        Cp[(size_t)r * D_] = (CT)acc[i][j][r];
    }
  }
}

// gemm3: 3 proj x (8192/256) x (1024/128) = 768 blocks = 3 exact rounds.
__global__ __launch_bounds__(512, 2)
void gemm3(const bf16_t* __restrict__ xr, const bf16_t* __restrict__ xk,
           const bf16_t* __restrict__ xv, const bf16_t* __restrict__ Wall,
           bf16_t* __restrict__ rbuf, bf16_t* __restrict__ kbuf, bf16_t* __restrict__ vbuf) {
  const int flat = blockIdx.x;                  // 0..767
  const int idx  = (flat & 7) * 96 + (flat >> 3);   // bijective XCD chunking
  const int proj = idx >> 8;
  const int tt   = idx & 255;
  const int mb   = tt >> 3;
  const int nb   = tt & 7;
  const bf16_t* A  = (proj == 0) ? xr : (proj == 1) ? xk : xv;
  const bf16_t* Bw = Wall + (size_t)proj * (1 << 20);
  bf16_t* C = (proj == 0) ? rbuf : (proj == 1) ? kbuf : vbuf;
  gemm_core<bf16_t>(A, Bw, C, mb * 256, nb * 128);
}

// gemm_bt: 32 x 8 = 256 blocks = 1 exact round; fp32 out (d_out).
__global__ __launch_bounds__(512, 2)
void gemm_bt(const bf16_t* __restrict__ A, const bf16_t* __restrict__ Bw,
             float* __restrict__ C) {
  const int flat = blockIdx.x;                  // 0..255
  const int idx  = (flat & 7) * 32 + (flat >> 3);
  const int mb   = idx >> 3;
  const int nb   = idx & 7;
  gemm_core<float>(A, Bw, C, mb * 256, nb * 128);
}

// ---------------------------------------------------------------------------
// bf16 chunk staging: row = 64 bf16 = 128 B; one wave-instr covers 8 rows
// (8 lanes x 16 B per row). 4 instrs stage a CL=32 chunk (4 KB).
// ---------------------------------------------------------------------------
__device__ __forceinline__ void stage_chunk_bf16(const char* gsrc, char* lds, int lane) {
  const int row = lane >> 3;            // 0..7 within group
  const int cb  = (lane & 7) * 16;
#pragma unroll
  for (int i = 0; i < 4; ++i) {
    size_t go = (size_t)(i * 8 + row) * (D_ * 2) + cb;
    async_copy16(gsrc + go, lds + i * 1024 + lane * 16);
  }
}

// ---------------------------------------------------------------------------
// Scan pass 1: chunk-local b-scan from -inf. G[bh][chunk][lane] (fp32).
// ---------------------------------------------------------------------------
__global__ __launch_bounds__(64)
void wkv_pass1(const bf16_t* __restrict__ kbuf, const float* __restrict__ time_decay,
               float* __restrict__ G) {
  __shared__ __align__(16) bf16_t ks[CL_][64];
  const int blk   = blockIdx.x;
  const int chunk = blk & (CHUNKS_ - 1);
  const int bh    = blk >> 6;
  const int b = bh >> 4, h = bh & 15;
  const int lane = threadIdx.x;
  const int c = h * HD_ + lane;
  const float w = -__expf(time_decay[c]);

  const size_t gbase = ((size_t)b * S_ + (size_t)chunk * CL_) * D_ + h * HD_;
  stage_chunk_bf16((const char*)(kbuf + gbase), (char*)&ks[0][0], lane);
  __builtin_amdgcn_s_waitcnt(0);
  __syncthreads();

  float g = -1e38f;
  for (int t = 0; t < CL_; ++t) {
    float kt = (float)ks[t][lane];
    float ww = g + w;
    float d2 = ww - kt;
    float em = __expf(-fabsf(d2));
    float e1b = (d2 >= 0.0f) ? 1.0f : em;
    float e2b = (d2 >= 0.0f) ? em : 1.0f;
    g = fmaxf(ww, kt) + __logf(e1b + e2b + 1e-8f);
  }
  G[(size_t)bh * (CHUNKS_ * 64) + chunk * 64 + lane] = g;
}

// ---------------------------------------------------------------------------
// Scan pass 2: stage G slab, exact LSE prefix for incoming b, store si_b,
// then the chunk's affine a-transfer (A = prod e1b, Bv = run from 0).
// ---------------------------------------------------------------------------
__global__ __launch_bounds__(64)
void wkv_pass2(const bf16_t* __restrict__ kbuf, const bf16_t* __restrict__ vbuf,
               const float* __restrict__ time_decay, const float* __restrict__ G,
               float* __restrict__ si_b, float* __restrict__ cs_A, float* __restrict__ cs_Bv) {
  __shared__ __align__(16) float Gs[CHUNKS_][64];   // 16 KB
  __shared__ __align__(16) bf16_t ks[CL_][64];      // 4 KB
  __shared__ __align__(16) bf16_t vs[CL_][64];      // 4 KB
  const int blk   = blockIdx.x;
  const int chunk = blk & (CHUNKS_ - 1);
  const int bh    = blk >> 6;
  const int b = bh >> 4, h = bh & 15;
  const int lane = threadIdx.x;
  const int c = h * HD_ + lane;
  const float w  = -__expf(time_decay[c]);
  const float wL = w * (float)CL_;

  const char* gg = (const char*)(G + (size_t)bh * (CHUNKS_ * 64));
#pragma unroll
  for (int i = 0; i < 16; ++i)
    async_copy16(gg + i * 1024 + lane * 16, (char*)&Gs[0][0] + i * 1024 + lane * 16);

  const size_t gbase = ((size_t)b * S_ + (size_t)chunk * CL_) * D_ + h * HD_;
  stage_chunk_bf16((const char*)(kbuf + gbase), (char*)&ks[0][0], lane);
  stage_chunk_bf16((const char*)(vbuf + gbase), (char*)&vs[0][0], lane);
  __builtin_amdgcn_s_waitcnt(0);
  __syncthreads();

  float bst = -1e38f;
  for (int ch = 0; ch < chunk; ++ch) {
    float g = Gs[ch][lane];
    float b1 = bst + wL;
    float dd = b1 - g;
    float em = __expf(-fabsf(dd));
    bst = fmaxf(b1, g) + __logf(1.0f + em);
  }
  const size_t so = (size_t)bh * (CHUNKS_ * 64) + chunk * 64 + lane;
  si_b[so] = bst;

  float a = 0.0f, Ap = 1.0f;
  for (int t = 0; t < CL_; ++t) {
    float kt = (float)ks[t][lane], vt = (float)vs[t][lane];
    float ww = bst + w;
    float d2 = ww - kt;
    float em = __expf(-fabsf(d2));
    float e1b = (d2 >= 0.0f) ? 1.0f : em;
    float e2b = (d2 >= 0.0f) ? em : 1.0f;
    a  = e1b * a + e2b * vt;
    Ap = Ap * e1b;
    bst = fmaxf(ww, kt) + __logf(e1b + e2b + 1e-8f);
  }
  cs_A [so] = Ap;
  cs_Bv[so] = a;
}

// ---------------------------------------------------------------------------
// Scan pass 3: affine prefix for incoming a, then exact reference steps;
// fuse sigmoid(r)*wkv and GroupNorm partials. rwkv written bf16.
// ---------------------------------------------------------------------------
__global__ __launch_bounds__(64)
void wkv_pass3(const bf16_t* __restrict__ rbuf, const bf16_t* __restrict__ kbuf,
               const bf16_t* __restrict__ vbuf,
               const float* __restrict__ time_decay, const float* __restrict__ time_first,
               const float* __restrict__ si_b,
               const float* __restrict__ cs_A, const float* __restrict__ cs_Bv,
               bf16_t* __restrict__ rwkv, float* __restrict__ psum, float* __restrict__ psq) {
  __shared__ __align__(16) char smem[32 * 1024];
  float (*As_)[64] = (float(*)[64])smem;                 // 16 KB
  float (*Bs_)[64] = (float(*)[64])(smem + 16384);       // 16 KB
  const int blk   = blockIdx.x;
  const int chunk = blk & (CHUNKS_ - 1);
  const int bh    = blk >> 6;
  const int b = bh >> 4, h = bh & 15;
  const int lane = threadIdx.x;
  const int c = h * HD_ + lane;
  const float w = -__expf(time_decay[c]);
  const float u = time_first[c];

  const char* ag = (const char*)(cs_A  + (size_t)bh * (CHUNKS_ * 64));
  const char* bg = (const char*)(cs_Bv + (size_t)bh * (CHUNKS_ * 64));
#pragma unroll
  for (int i = 0; i < 16; ++i) {
    async_copy16(ag + i * 1024 + lane * 16, (char*)&As_[0][0] + i * 1024 + lane * 16);
    async_copy16(bg + i * 1024 + lane * 16, (char*)&Bs_[0][0] + i * 1024 + lane * 16);
  }
  const size_t so = (size_t)bh * (CHUNKS_ * 64) + chunk * 64 + lane;
  float bst = si_b[so];
  __builtin_amdgcn_s_waitcnt(0);
  __syncthreads();

  float a = 0.0f;
  for (int ch = 0; ch < chunk; ++ch)
    a = As_[ch][lane] * a + Bs_[ch][lane];
  __syncthreads();   // done with As_/Bs_ before LDS reuse

  bf16_t (*rs)[64] = (bf16_t(*)[64])smem;                 // 4 KB each
  bf16_t (*ks)[64] = (bf16_t(*)[64])(smem + 4096);
  bf16_t (*vs)[64] = (bf16_t(*)[64])(smem + 8192);
  const size_t gbase = ((size_t)b * S_ + (size_t)chunk * CL_) * D_ + h * HD_;
  stage_chunk_bf16((const char*)(rbuf + gbase), (char*)&rs[0][0], lane);
  stage_chunk_bf16((const char*)(kbuf + gbase), (char*)&ks[0][0], lane);
  stage_chunk_bf16((const char*)(vbuf + gbase), (char*)&vs[0][0], lane);
  __builtin_amdgcn_s_waitcnt(0);
  __syncthreads();

  float sum = 0.0f, sq = 0.0f;
  size_t widx = gbase + lane;
  for (int t = 0; t < CL_; ++t) {
    float kt = (float)ks[t][lane], vt = (float)vs[t][lane], rt = (float)rs[t][lane];
    float wk = kt + u;
    float d1 = bst - wk;
    float em1 = __expf(-fabsf(d1));
    float e1 = (d1 >= 0.0f) ? 1.0f : em1;
    float e2 = (d1 >= 0.0f) ? em1 : 1.0f;
    float out = __fdividef(e1 * a + e2 * vt, e1 + e2 + 1e-8f);

    float ww = bst + w;
    float d2 = ww - kt;
    float em2 = __expf(-fabsf(d2));
    float e1b = (d2 >= 0.0f) ? 1.0f : em2;
    float e2b = (d2 >= 0.0f) ? em2 : 1.0f;
    a   = e1b * a + e2b * vt;
    bst = fmaxf(ww, kt) + __logf(e1b + e2b + 1e-8f);

    float sig = __fdividef(1.0f, 1.0f + __expf(-rt));
    float o2 = sig * out;
    rwkv[widx] = (bf16_t)o2;
    sum += o2; sq += o2 * o2;
    widx += D_;
  }

#pragma unroll
  for (int off = 32; off > 0; off >>= 1) {
    sum += __shfl_down(sum, off);
    sq  += __shfl_down(sq, off);
  }
  if (lane == 0) {
    psum[bh * CHUNKS_ + chunk] = sum;
    psq [bh * CHUNKS_ + chunk] = sq;
  }
}

// ---------------------------------------------------------------------------
// GroupNorm: stats finalize fused into apply+cast. bf16 in/out.
// ---------------------------------------------------------------------------
__global__ __launch_bounds__(256)
void norm_cast(const bf16_t* __restrict__ rwkv,
               const float* __restrict__ psum, const float* __restrict__ psq,
               const float* __restrict__ gamma, const float* __restrict__ beta,
               bf16_t* __restrict__ normed) {
  __shared__ float smean[4], srstd[4];
  const int tid = threadIdx.x;
  const int lane = tid & 63;
  const int wj = tid >> 6;
  int idx0 = blockIdx.x * 256;
  int d0 = idx0 & (D_ - 1);
  int bb = idx0 / (S_ * D_);
  int bh = bb * H_ + (d0 >> 6) + wj;

  float s = psum[bh * CHUNKS_ + lane];
  float q = psq [bh * CHUNKS_ + lane];
#pragma unroll
  for (int off = 32; off > 0; off >>= 1) {
    s += __shfl_down(s, off);
    q += __shfl_down(q, off);
  }
  if (lane == 0) {
    const float n = (float)(S_ * HD_);
    float mean = s / n;
    float var  = q / n - mean * mean;
    smean[wj] = mean;
    srstd[wj] = rsqrtf(var + 1e-5f);
  }
  __syncthreads();

  int idx = idx0 + tid;
  int d = idx & (D_ - 1);
  float v = ((float)rwkv[idx] - smean[wj]) * srstd[wj] * gamma[d] + beta[d];
  normed[idx] = (bf16_t)v;
}

// ---------------------------------------------------------------------------
extern "C" void kernel_launch(void* const* d_in, const int* in_sizes, int n_in,
                              void* d_out, int out_size, void* d_ws, size_t ws_size,
                              hipStream_t stream) {
  const float* x     = (const float*)d_in[0];
  const float* tmr   = (const float*)d_in[1];
  const float* tmk   = (const float*)d_in[2];
  const float* tmv   = (const float*)d_in[3];
  const float* Wr    = (const float*)d_in[4];
  const float* Wk    = (const float*)d_in[5];
  const float* Wv    = (const float*)d_in[6];
  const float* Wo    = (const float*)d_in[7];
  const float* td    = (const float*)d_in[8];
  const float* tf    = (const float*)d_in[9];
  const float* gamma = (const float*)d_in[10];
  const float* beta  = (const float*)d_in[11];

  char* ws = (char*)d_ws;
  const size_t MB = 1024 * 1024;
  bf16_t* W_bf    = (bf16_t*)(ws + 0 * MB);    // Wr,Wk,Wv,Wo bf16, 8 MB
  bf16_t* Wo_bf   = (bf16_t*)(ws + 6 * MB);
  bf16_t* xr      = (bf16_t*)(ws + 8 * MB);    // 16 MB each
  bf16_t* xk      = (bf16_t*)(ws + 24 * MB);
  bf16_t* xv      = (bf16_t*)(ws + 40 * MB);
  // scan scratch reuses xk/xv region (dead after gemm3)
  float*  G       = (float*)(ws + 24 * MB);    // 1 MB each
  float*  cs_A    = (float*)(ws + 25 * MB);
  float*  cs_Bv   = (float*)(ws + 26 * MB);
  float*  si_b    = (float*)(ws + 27 * MB);
  float*  psum    = (float*)(ws + 28 * MB);    // 16 KB each
  float*  psq     = (float*)(ws + 28 * MB + 64 * 1024);
  bf16_t* rwkv    = (bf16_t*)(ws + 30 * MB);   // 16 MB (in dead xk/xv space)
  bf16_t* rbuf    = (bf16_t*)(ws + 56 * MB);   // 16 MB each, bf16
  bf16_t* kbuf    = (bf16_t*)(ws + 72 * MB);
  bf16_t* vbuf    = (bf16_t*)(ws + 88 * MB);
  bf16_t* normed  = xr;                        // xr dead after gemm3

  float* outp = (float*)d_out;

  pre_kernel<<<(12 * 1024 * 1024) / 256, 256, 0, stream>>>(
      Wr, Wk, Wv, Wo, W_bf, x, tmr, tmk, tmv, xr, xk, xv);

  gemm3<<<768, 512, 0, stream>>>(xr, xk, xv, W_bf, rbuf, kbuf, vbuf);

  wkv_pass1<<<B_ * H_ * CHUNKS_, 64, 0, stream>>>(kbuf, td, G);
  wkv_pass2<<<B_ * H_ * CHUNKS_, 64, 0, stream>>>(kbuf, vbuf, td, G, si_b, cs_A, cs_Bv);
  wkv_pass3<<<B_ * H_ * CHUNKS_, 64, 0, stream>>>(rbuf, kbuf, vbuf, td, tf,
                                                  si_b, cs_A, cs_Bv, rwkv, psum, psq);

  norm_cast<<<(M_ * D_) / 256, 256, 0, stream>>>(rwkv, psum, psq, gamma, beta, normed);

  gemm_bt<<<256, 512, 0, stream>>>(normed, Wo_bf, outp);
}

// Round 2
// 300.587 us; speedup vs baseline: 1.0563x; 1.0364x over previous
//
#include <hip/hip_runtime.h>
#include <cstdint>
#include <cstddef>

#define B_  4
#define S_  2048
#define D_  1024
#define H_  16
#define HD_ 64
#define M_  (B_ * S_)   // 8192 rows

#define CHUNKS_ 64      // parallel chunks per (b,h) sequence
#define CL_     32      // chunk length; CHUNKS_*CL_ == S_

typedef __bf16 bf16_t;
typedef bf16_t bf16x8 __attribute__((ext_vector_type(8)));
typedef float  floatx4 __attribute__((ext_vector_type(4)));

// ---------------------------------------------------------------------------
// async 16B global -> LDS copy (gfx950). LDS dest is wave-uniform base +
// lane*16 (m104/m108); all uses below pass lds = base + lane*16 exactly.
// ---------------------------------------------------------------------------
__device__ __forceinline__ void async_copy16(const void* gmem, void* lds) {
  __builtin_amdgcn_global_load_lds(
      (__attribute__((address_space(1))) void*)const_cast<void*>(gmem),
      (__attribute__((address_space(3))) void*)lds,
      16, 0, 0);
}

// ---------------------------------------------------------------------------
// Fused prologue: weight fp32->bf16 cast (4M elems) + token-shift mix (8M).
// ---------------------------------------------------------------------------
__global__ void pre_kernel(const float* __restrict__ w0, const float* __restrict__ w1,
                           const float* __restrict__ w2, const float* __restrict__ w3,
                           bf16_t* __restrict__ wout,
                           const float* __restrict__ x,
                           const float* __restrict__ tmr, const float* __restrict__ tmk,
                           const float* __restrict__ tmv,
                           bf16_t* __restrict__ xr, bf16_t* __restrict__ xk,
                           bf16_t* __restrict__ xv) {
  const int ONE_M = 1 << 20;
  int gid = blockIdx.x * blockDim.x + threadIdx.x;
  if (gid < 4 * ONE_M) {
    const float* src = (gid < ONE_M) ? w0 : (gid < 2 * ONE_M) ? w1 : (gid < 3 * ONE_M) ? w2 : w3;
    wout[gid] = (bf16_t)src[gid & (ONE_M - 1)];
  } else {
    int idx = gid - 4 * ONE_M;                 // 0 .. 8M-1
    int d = idx & (D_ - 1);
    int t = (idx / D_) & (S_ - 1);
    float xc = x[idx];
    float xp = (t == 0) ? 0.0f : x[idx - D_];
    float mr = tmr[d], mk = tmk[d], mv = tmv[d];
    xr[idx] = (bf16_t)(xc * mr + xp * (1.0f - mr));
    xk[idx] = (bf16_t)(xc * mk + xp * (1.0f - mk));
    xv[idx] = (bf16_t)(xc * mv + xp * (1.0f - mv));
  }
}

// ---------------------------------------------------------------------------
// r10: T3 fine-phase + T4 counted-vmcnt + T5 setprio GEMM core.
//   BM=256 BN=128 BK=64, 512 thr / 8 waves (4M x 2N), per-wave 64x64.
//   3-slot LDS rotation (144 KiB), depth-2 prefetch, vmcnt(6) per tile.
//   Per K-tile: 2 phases x 16 MFMA (template density). Phase 1 reads all B
//   (kept live in regs across the tile) + A rows 0-1; phase 2 reads A rows
//   2-3 only. Stage issues sit between ds_reads and lgkmcnt(0) so VMEM
//   issue hides under ds_read latency. lgkmcnt(0)+sched_barrier(0) per
//   rule #18; setprio(1) around each MFMA cluster (T5). One barrier +
//   one counted vmcnt per K-tile (slot rotation needs no mid-tile barrier).
//   T2 swizzle both-sides (rule #21): LDS[r][c] = G[r][c ^ (r&7)] in 16B
//   units via pre-swizzled source col; reads XOR the same pattern.
// ---------------------------------------------------------------------------
#define STG(kt, la, lb, p) do {                                            \
    const char* _ga = Abase + (size_t)(kt) * 128;                          \
    const char* _gb = Bbase + (size_t)(kt) * 128;                          \
    async_copy16(_ga + (size_t)(((p) * 2 + 0) * 64 + r8) * 2048 + cbs,     \
                 (la) + ((p) * 2 + 0) * 8192 + tid * 16);                  \
    async_copy16(_ga + (size_t)(((p) * 2 + 1) * 64 + r8) * 2048 + cbs,     \
                 (la) + ((p) * 2 + 1) * 8192 + tid * 16);                  \
    async_copy16(_gb + (size_t)((p) * 64 + r8) * 2048 + cbs,               \
                 (lb) + (p) * 8192 + tid * 16);                            \
  } while (0)

// Phase 1: read B[0..3][ks0,ks1] + A[0..1][ks0,ks1]; STMT (stage issues);
// wait; MFMA acc rows 0-1 (16 MFMA).
#define PH1(la, lb, STMT) do {                                             \
    _Pragma("unroll")                                                      \
    for (int _j = 0; _j < 4; ++_j) {                                       \
      const char* _rb = (lb) + (wn * 64 + _j * 16 + l15) * 128;            \
      bfr[_j][0] = *(const bf16x8*)(_rb + ((quad * 16) ^ swz));            \
      bfr[_j][1] = *(const bf16x8*)(_rb + ((64 + quad * 16) ^ swz));       \
    }                                                                      \
    _Pragma("unroll")                                                      \
    for (int _i = 0; _i < 2; ++_i) {                                       \
      const char* _ra = (la) + (wm * 64 + _i * 16 + l15) * 128;            \
      afr[_i][0] = *(const bf16x8*)(_ra + ((quad * 16) ^ swz));            \
      afr[_i][1] = *(const bf16x8*)(_ra + ((64 + quad * 16) ^ swz));       \
    }                                                                      \
    STMT;                                                                  \
    asm volatile("s_waitcnt lgkmcnt(0)" ::: "memory");                     \
    __builtin_amdgcn_sched_barrier(0);                                     \
    __builtin_amdgcn_s_setprio(1);                                         \
    _Pragma("unroll")                                                      \
    for (int _k = 0; _k < 2; ++_k)                                         \
      _Pragma("unroll")                                                    \
      for (int _i = 0; _i < 2; ++_i)                                       \
        _Pragma("unroll")                                                  \
        for (int _j = 0; _j < 4; ++_j)                                     \
          acc[_i][_j] = __builtin_amdgcn_mfma_f32_16x16x32_bf16(           \
              afr[_i][_k], bfr[_j][_k], acc[_i][_j], 0, 0, 0);             \
    __builtin_amdgcn_s_setprio(0);                                         \
  } while (0)

// Phase 2: read A[2..3]; STMT; wait; MFMA acc rows 2-3 (16 MFMA, B from regs).
#define PH2(la, STMT) do {                                                 \
    _Pragma("unroll")                                                      \
    for (int _i = 0; _i < 2; ++_i) {                                       \
      const char* _ra = (la) + (wm * 64 + (2 + _i) * 16 + l15) * 128;      \
      afr[_i][0] = *(const bf16x8*)(_ra + ((quad * 16) ^ swz));            \
      afr[_i][1] = *(const bf16x8*)(_ra + ((64 + quad * 16) ^ swz));       \
    }                                                                      \
    STMT;                                                                  \
    asm volatile("s_waitcnt lgkmcnt(0)" ::: "memory");                     \
    __builtin_amdgcn_sched_barrier(0);                                     \
    __builtin_amdgcn_s_setprio(1);                                         \
    _Pragma("unroll")                                                      \
    for (int _k = 0; _k < 2; ++_k)                                         \
      _Pragma("unroll")                                                    \
      for (int _i = 0; _i < 2; ++_i)                                       \
        _Pragma("unroll")                                                  \
        for (int _j = 0; _j < 4; ++_j)                                     \
          acc[2 + _i][_j] = __builtin_amdgcn_mfma_f32_16x16x32_bf16(       \
              afr[_i][_k], bfr[_j][_k], acc[2 + _i][_j], 0, 0, 0);         \
    __builtin_amdgcn_s_setprio(0);                                         \
  } while (0)

// counted vmcnt + raw barrier; asm memory clobbers fence compiler reordering
#define FENCE_BAR(N) do {                                                  \
    asm volatile("s_waitcnt vmcnt(" #N ")" ::: "memory");                  \
    __builtin_amdgcn_s_barrier();                                          \
    asm volatile("" ::: "memory");                                         \
  } while (0)

template <typename CT>
__device__ __forceinline__ void gemm_core(const bf16_t* __restrict__ A,
                                          const bf16_t* __restrict__ Bw,
                                          CT* __restrict__ C, int m0, int n0) {
  __shared__ __align__(16) bf16_t As[3][256][64];   // 96 KiB
  __shared__ __align__(16) bf16_t Bs[3][128][64];   // 48 KiB

  const int tid  = threadIdx.x;
  const int lane = tid & 63;
  const int wave = tid >> 6;       // 0..7
  const int wm   = wave >> 1;      // 0..3  (M)
  const int wn   = wave & 1;       // 0..1  (N)
  const int l15  = lane & 15;
  const int quad = lane >> 4;
  const int r8   = tid >> 3;                       // staging row-within-64
  const int cbs  = (((tid & 7) ^ (r8 & 7)) << 4);  // pre-swizzled src col
  const int swz  = (l15 & 7) << 4;                 // read-side XOR

  const char* Abase = (const char*)(A + (size_t)m0 * D_);
  const char* Bbase = (const char*)(Bw + (size_t)n0 * D_);

  char* const a0 = (char*)&As[0][0][0];
  char* const a1 = a0 + 32768;
  char* const a2 = a1 + 32768;
  char* const b0 = (char*)&Bs[0][0][0];
  char* const b1 = b0 + 16384;
  char* const b2 = b1 + 16384;

  floatx4 acc[4][4] = {};
  bf16x8 afr[2][2], bfr[4][2];

  // prologue: tiles 0,1 in flight; wait tile0 (own 6 of 12) then barrier
  STG(0, a0, b0, 0); STG(0, a0, b0, 1);
  STG(1, a1, b1, 0); STG(1, a1, b1, 1);
  FENCE_BAR(6);

  char *aC = a0, *aN = a1, *aF = a2;
  char *bC = b0, *bN = b1, *bF = b2;

  // K = 1024 -> 16 tiles of BK=64. Main loop covers t=0..13 (t+2 <= 15).
#pragma unroll 1
  for (int t = 0; t < 14; ++t) {
    PH1(aC, bC, STG(t + 2, aF, bF, 0));
    PH2(aC,     STG(t + 2, aF, bF, 1));
    FENCE_BAR(6);                // tile t+1 landed; t+2's 6 stay in flight
    char* x;
    x = aC; aC = aN; aN = aF; aF = x;
    x = bC; bC = bN; bN = bF; bF = x;
  }
  // t = 14: nothing left to stage; drain tile15's loads at the fence
  PH1(aC, bC, (void)0);
  PH2(aC,     (void)0);
  FENCE_BAR(0);
  // t = 15
  PH1(aN, bN, (void)0);
  PH2(aN,     (void)0);

#pragma unroll
  for (int i = 0; i < 4; ++i) {
#pragma unroll
    for (int j = 0; j < 4; ++j) {
      int row = m0 + wm * 64 + i * 16 + quad * 4;
      int col = n0 + wn * 64 + j * 16 + l15;
      CT* Cp = C + (size_t)row * D_ + col;
#pragma unroll
      for (int r = 0; r < 4; ++r)
        Cp[(size_t)r * D_] = (CT)acc[i][j][r];
    }
  }
}

// gemm3: 3 proj x (8192/256) x (1024/128) = 768 blocks = 3 exact rounds.
__global__ __launch_bounds__(512, 2)
void gemm3(const bf16_t* __restrict__ xr, const bf16_t* __restrict__ xk,
           const bf16_t* __restrict__ xv, const bf16_t* __restrict__ Wall,
           bf16_t* __restrict__ rbuf, bf16_t* __restrict__ kbuf, bf16_t* __restrict__ vbuf) {
  const int flat = blockIdx.x;                  // 0..767
  const int idx  = (flat & 7) * 96 + (flat >> 3);   // bijective XCD chunking
  const int proj = idx >> 8;
  const int tt   = idx & 255;
  const int mb   = tt >> 3;
  const int nb   = tt & 7;
  const bf16_t* A  = (proj == 0) ? xr : (proj == 1) ? xk : xv;
  const bf16_t* Bw = Wall + (size_t)proj * (1 << 20);
  bf16_t* C = (proj == 0) ? rbuf : (proj == 1) ? kbuf : vbuf;
  gemm_core<bf16_t>(A, Bw, C, mb * 256, nb * 128);
}

// gemm_bt: 32 x 8 = 256 blocks = 1 exact round; fp32 out (d_out).
__global__ __launch_bounds__(512, 2)
void gemm_bt(const bf16_t* __restrict__ A, const bf16_t* __restrict__ Bw,
             float* __restrict__ C) {
  const int flat = blockIdx.x;                  // 0..255
  const int idx  = (flat & 7) * 32 + (flat >> 3);
  const int mb   = idx >> 3;
  const int nb   = idx & 7;
  gemm_core<float>(A, Bw, C, mb * 256, nb * 128);
}

// ---------------------------------------------------------------------------
// bf16 chunk staging: row = 64 bf16 = 128 B; one wave-instr covers 8 rows
// (8 lanes x 16 B per row). 4 instrs stage a CL=32 chunk (4 KB).
// ---------------------------------------------------------------------------
__device__ __forceinline__ void stage_chunk_bf16(const char* gsrc, char* lds, int lane) {
  const int row = lane >> 3;            // 0..7 within group
  const int cb  = (lane & 7) * 16;
#pragma unroll
  for (int i = 0; i < 4; ++i) {
    size_t go = (size_t)(i * 8 + row) * (D_ * 2) + cb;
    async_copy16(gsrc + go, lds + i * 1024 + lane * 16);
  }
}

// ---------------------------------------------------------------------------
// Scan pass 1: chunk-local b-scan from -inf. G[bh][chunk][lane] (fp32).
// ---------------------------------------------------------------------------
__global__ __launch_bounds__(64)
void wkv_pass1(const bf16_t* __restrict__ kbuf, const float* __restrict__ time_decay,
               float* __restrict__ G) {
  __shared__ __align__(16) bf16_t ks[CL_][64];
  const int blk   = blockIdx.x;
  const int chunk = blk & (CHUNKS_ - 1);
  const int bh    = blk >> 6;
  const int b = bh >> 4, h = bh & 15;
  const int lane = threadIdx.x;
  const int c = h * HD_ + lane;
  const float w = -__expf(time_decay[c]);

  const size_t gbase = ((size_t)b * S_ + (size_t)chunk * CL_) * D_ + h * HD_;
  stage_chunk_bf16((const char*)(kbuf + gbase), (char*)&ks[0][0], lane);
  __builtin_amdgcn_s_waitcnt(0);
  __syncthreads();

  float g = -1e38f;
  for (int t = 0; t < CL_; ++t) {
    float kt = (float)ks[t][lane];
    float ww = g + w;
    float d2 = ww - kt;
    float em = __expf(-fabsf(d2));
    float e1b = (d2 >= 0.0f) ? 1.0f : em;
    float e2b = (d2 >= 0.0f) ? em : 1.0f;
    g = fmaxf(ww, kt) + __logf(e1b + e2b + 1e-8f);
  }
  G[(size_t)bh * (CHUNKS_ * 64) + chunk * 64 + lane] = g;
}

// ---------------------------------------------------------------------------
// Scan pass 2: stage G slab, exact LSE prefix for incoming b, store si_b,
// then the chunk's affine a-transfer (A = prod e1b, Bv = run from 0).
// ---------------------------------------------------------------------------
__global__ __launch_bounds__(64)
void wkv_pass2(const bf16_t* __restrict__ kbuf, const bf16_t* __restrict__ vbuf,
               const float* __restrict__ time_decay, const float* __restrict__ G,
               float* __restrict__ si_b, float* __restrict__ cs_A, float* __restrict__ cs_Bv) {
  __shared__ __align__(16) float Gs[CHUNKS_][64];   // 16 KB
  __shared__ __align__(16) bf16_t ks[CL_][64];      // 4 KB
  __shared__ __align__(16) bf16_t vs[CL_][64];      // 4 KB
  const int blk   = blockIdx.x;
  const int chunk = blk & (CHUNKS_ - 1);
  const int bh    = blk >> 6;
  const int b = bh >> 4, h = bh & 15;
  const int lane = threadIdx.x;
  const int c = h * HD_ + lane;
  const float w  = -__expf(time_decay[c]);
  const float wL = w * (float)CL_;

  const char* gg = (const char*)(G + (size_t)bh * (CHUNKS_ * 64));
#pragma unroll
  for (int i = 0; i < 16; ++i)
    async_copy16(gg + i * 1024 + lane * 16, (char*)&Gs[0][0] + i * 1024 + lane * 16);

  const size_t gbase = ((size_t)b * S_ + (size_t)chunk * CL_) * D_ + h * HD_;
  stage_chunk_bf16((const char*)(kbuf + gbase), (char*)&ks[0][0], lane);
  stage_chunk_bf16((const char*)(vbuf + gbase), (char*)&vs[0][0], lane);
  __builtin_amdgcn_s_waitcnt(0);
  __syncthreads();

  float bst = -1e38f;
  for (int ch = 0; ch < chunk; ++ch) {
    float g = Gs[ch][lane];
    float b1 = bst + wL;
    float dd = b1 - g;
    float em = __expf(-fabsf(dd));
    bst = fmaxf(b1, g) + __logf(1.0f + em);
  }
  const size_t so = (size_t)bh * (CHUNKS_ * 64) + chunk * 64 + lane;
  si_b[so] = bst;

  float a = 0.0f, Ap = 1.0f;
  for (int t = 0; t < CL_; ++t) {
    float kt = (float)ks[t][lane], vt = (float)vs[t][lane];
    float ww = bst + w;
    float d2 = ww - kt;
    float em = __expf(-fabsf(d2));
    float e1b = (d2 >= 0.0f) ? 1.0f : em;
    float e2b = (d2 >= 0.0f) ? em : 1.0f;
    a  = e1b * a + e2b * vt;
    Ap = Ap * e1b;
    bst = fmaxf(ww, kt) + __logf(e1b + e2b + 1e-8f);
  }
  cs_A [so] = Ap;
  cs_Bv[so] = a;
}

// ---------------------------------------------------------------------------
// Scan pass 3: affine prefix for incoming a, then exact reference steps;
// fuse sigmoid(r)*wkv and GroupNorm partials. rwkv written bf16.
// ---------------------------------------------------------------------------
__global__ __launch_bounds__(64)
void wkv_pass3(const bf16_t* __restrict__ rbuf, const bf16_t* __restrict__ kbuf,
               const bf16_t* __restrict__ vbuf,
               const float* __restrict__ time_decay, const float* __restrict__ time_first,
               const float* __restrict__ si_b,
               const float* __restrict__ cs_A, const float* __restrict__ cs_Bv,
               bf16_t* __restrict__ rwkv, float* __restrict__ psum, float* __restrict__ psq) {
  __shared__ __align__(16) char smem[32 * 1024];
  float (*As_)[64] = (float(*)[64])smem;                 // 16 KB
  float (*Bs_)[64] = (float(*)[64])(smem + 16384);       // 16 KB
  const int blk   = blockIdx.x;
  const int chunk = blk & (CHUNKS_ - 1);
  const int bh    = blk >> 6;
  const int b = bh >> 4, h = bh & 15;
  const int lane = threadIdx.x;
  const int c = h * HD_ + lane;
  const float w = -__expf(time_decay[c]);
  const float u = time_first[c];

  const char* ag = (const char*)(cs_A  + (size_t)bh * (CHUNKS_ * 64));
  const char* bg = (const char*)(cs_Bv + (size_t)bh * (CHUNKS_ * 64));
#pragma unroll
  for (int i = 0; i < 16; ++i) {
    async_copy16(ag + i * 1024 + lane * 16, (char*)&As_[0][0] + i * 1024 + lane * 16);
    async_copy16(bg + i * 1024 + lane * 16, (char*)&Bs_[0][0] + i * 1024 + lane * 16);
  }
  const size_t so = (size_t)bh * (CHUNKS_ * 64) + chunk * 64 + lane;
  float bst = si_b[so];
  __builtin_amdgcn_s_waitcnt(0);
  __syncthreads();

  float a = 0.0f;
  for (int ch = 0; ch < chunk; ++ch)
    a = As_[ch][lane] * a + Bs_[ch][lane];
  __syncthreads();   // done with As_/Bs_ before LDS reuse

  bf16_t (*rs)[64] = (bf16_t(*)[64])smem;                 // 4 KB each
  bf16_t (*ks)[64] = (bf16_t(*)[64])(smem + 4096);
  bf16_t (*vs)[64] = (bf16_t(*)[64])(smem + 8192);
  const size_t gbase = ((size_t)b * S_ + (size_t)chunk * CL_) * D_ + h * HD_;
  stage_chunk_bf16((const char*)(rbuf + gbase), (char*)&rs[0][0], lane);
  stage_chunk_bf16((const char*)(kbuf + gbase), (char*)&ks[0][0], lane);
  stage_chunk_bf16((const char*)(vbuf + gbase), (char*)&vs[0][0], lane);
  __builtin_amdgcn_s_waitcnt(0);
  __syncthreads();

  float sum = 0.0f, sq = 0.0f;
  size_t widx = gbase + lane;
  for (int t = 0; t < CL_; ++t) {
    float kt = (float)ks[t][lane], vt = (float)vs[t][lane], rt = (float)rs[t][lane];
    float wk = kt + u;
    float d1 = bst - wk;
    float em1 = __expf(-fabsf(d1));
    float e1 = (d1 >= 0.0f) ? 1.0f : em1;
    float e2 = (d1 >= 0.0f) ? em1 : 1.0f;
    float out = __fdividef(e1 * a + e2 * vt, e1 + e2 + 1e-8f);

    float ww = bst + w;
    float d2 = ww - kt;
    float em2 = __expf(-fabsf(d2));
    float e1b = (d2 >= 0.0f) ? 1.0f : em2;
    float e2b = (d2 >= 0.0f) ? em2 : 1.0f;
    a   = e1b * a + e2b * vt;
    bst = fmaxf(ww, kt) + __logf(e1b + e2b + 1e-8f);

    float sig = __fdividef(1.0f, 1.0f + __expf(-rt));
    float o2 = sig * out;
    rwkv[widx] = (bf16_t)o2;
    sum += o2; sq += o2 * o2;
    widx += D_;
  }

#pragma unroll
  for (int off = 32; off > 0; off >>= 1) {
    sum += __shfl_down(sum, off);
    sq  += __shfl_down(sq, off);
  }
  if (lane == 0) {
    psum[bh * CHUNKS_ + chunk] = sum;
    psq [bh * CHUNKS_ + chunk] = sq;
  }
}

// ---------------------------------------------------------------------------
// GroupNorm: stats finalize fused into apply+cast. bf16 in/out.
// ---------------------------------------------------------------------------
__global__ __launch_bounds__(256)
void norm_cast(const bf16_t* __restrict__ rwkv,
               const float* __restrict__ psum, const float* __restrict__ psq,
               const float* __restrict__ gamma, const float* __restrict__ beta,
               bf16_t* __restrict__ normed) {
  __shared__ float smean[4], srstd[4];
  const int tid = threadIdx.x;
  const int lane = tid & 63;
  const int wj = tid >> 6;
  int idx0 = blockIdx.x * 256;
  int d0 = idx0 & (D_ - 1);
  int bb = idx0 / (S_ * D_);
  int bh = bb * H_ + (d0 >> 6) + wj;

  float s = psum[bh * CHUNKS_ + lane];
  float q = psq [bh * CHUNKS_ + lane];
#pragma unroll
  for (int off = 32; off > 0; off >>= 1) {
    s += __shfl_down(s, off);
    q += __shfl_down(q, off);
  }
  if (lane == 0) {
    const float n = (float)(S_ * HD_);
    float mean = s / n;
    float var  = q / n - mean * mean;
    smean[wj] = mean;
    srstd[wj] = rsqrtf(var + 1e-5f);
  }
  __syncthreads();

  int idx = idx0 + tid;
  int d = idx & (D_ - 1);
  float v = ((float)rwkv[idx] - smean[wj]) * srstd[wj] * gamma[d] + beta[d];
  normed[idx] = (bf16_t)v;
}

// ---------------------------------------------------------------------------
extern "C" void kernel_launch(void* const* d_in, const int* in_sizes, int n_in,
                              void* d_out, int out_size, void* d_ws, size_t ws_size,
                              hipStream_t stream) {
  const float* x     = (const float*)d_in[0];
  const float* tmr   = (const float*)d_in[1];
  const float* tmk   = (const float*)d_in[2];
  const float* tmv   = (const float*)d_in[3];
  const float* Wr    = (const float*)d_in[4];
  const float* Wk    = (const float*)d_in[5];
  const float* Wv    = (const float*)d_in[6];
  const float* Wo    = (const float*)d_in[7];
  const float* td    = (const float*)d_in[8];
  const float* tf    = (const float*)d_in[9];
  const float* gamma = (const float*)d_in[10];
  const float* beta  = (const float*)d_in[11];

  char* ws = (char*)d_ws;
  const size_t MB = 1024 * 1024;
  bf16_t* W_bf    = (bf16_t*)(ws + 0 * MB);    // Wr,Wk,Wv,Wo bf16, 8 MB
  bf16_t* Wo_bf   = (bf16_t*)(ws + 6 * MB);
  bf16_t* xr      = (bf16_t*)(ws + 8 * MB);    // 16 MB each
  bf16_t* xk      = (bf16_t*)(ws + 24 * MB);
  bf16_t* xv      = (bf16_t*)(ws + 40 * MB);
  // scan scratch reuses xk/xv region (dead after gemm3)
  float*  G       = (float*)(ws + 24 * MB);    // 1 MB each
  float*  cs_A    = (float*)(ws + 25 * MB);
  float*  cs_Bv   = (float*)(ws + 26 * MB);
  float*  si_b    = (float*)(ws + 27 * MB);
  float*  psum    = (float*)(ws + 28 * MB);    // 16 KB each
  float*  psq     = (float*)(ws + 28 * MB + 64 * 1024);
  bf16_t* rwkv    = (bf16_t*)(ws + 30 * MB);   // 16 MB (in dead xk/xv space)
  bf16_t* rbuf    = (bf16_t*)(ws + 56 * MB);   // 16 MB each, bf16
  bf16_t* kbuf    = (bf16_t*)(ws + 72 * MB);
  bf16_t* vbuf    = (bf16_t*)(ws + 88 * MB);
  bf16_t* normed  = xr;                        // xr dead after gemm3

  float* outp = (float*)d_out;

  pre_kernel<<<(12 * 1024 * 1024) / 256, 256, 0, stream>>>(
      Wr, Wk, Wv, Wo, W_bf, x, tmr, tmk, tmv, xr, xk, xv);

  gemm3<<<768, 512, 0, stream>>>(xr, xk, xv, W_bf, rbuf, kbuf, vbuf);

  wkv_pass1<<<B_ * H_ * CHUNKS_, 64, 0, stream>>>(kbuf, td, G);
  wkv_pass2<<<B_ * H_ * CHUNKS_, 64, 0, stream>>>(kbuf, vbuf, td, G, si_b, cs_A, cs_Bv);
  wkv_pass3<<<B_ * H_ * CHUNKS_, 64, 0, stream>>>(rbuf, kbuf, vbuf, td, tf,
                                                  si_b, cs_A, cs_Bv, rwkv, psum, psq);

  norm_cast<<<(M_ * D_) / 256, 256, 0, stream>>>(rwkv, psum, psq, gamma, beta, normed);

  gemm_bt<<<256, 512, 0, stream>>>(normed, Wo_bf, outp);
}